// Round 14
// baseline (431.715 us; speedup 1.0000x reference)
//
#include <hip/hip_runtime.h>
#include <hip/hip_bf16.h>

typedef unsigned short u16;
typedef unsigned char u8;
typedef short bf16x8 __attribute__((ext_vector_type(8)));
typedef float f32x4 __attribute__((ext_vector_type(4)));
typedef float f32x2 __attribute__((ext_vector_type(2)));

__device__ __forceinline__ float blo(unsigned u) { return __uint_as_float(u << 16); }
__device__ __forceinline__ float bhi(unsigned u) { return __uint_as_float(u & 0xFFFF0000u); }
__device__ __forceinline__ u16 f2bf(float f) {
    unsigned x = __float_as_uint(f);
    x += 0x7fffu + ((x >> 16) & 1u);   // round-to-nearest-even
    return (u16)(x >> 16);
}
__device__ __forceinline__ u8 f2fp8(float f) {
    return (u8)(__builtin_amdgcn_cvt_pk_fp8_f32(f, f, 0, false) & 0xFF);
}

#define CAP 80
#define NB_SHIFT 7
#define BNODES 128
#define CAPB 4608
#define MAXNB 800
#define TILE 4096
#define PK 136   // padded K stride (bf16 elems) for 128-K LDS stage

// ---------------- zero bucket counters ----------------

__global__ __launch_bounds__(256) void k_zero(int* g, int n) {
    int i = blockIdx.x * 256 + threadIdx.x;
    if (i < n) g[i] = 0;
}

// ---------------- W1 [256][128] f32 -> W1t [128][256] bf16 ----------------

__global__ __launch_bounds__(256) void k_prepw(const float* __restrict__ W1, u16* __restrict__ W1t) {
    int t = blockIdx.x * 256 + threadIdx.x;   // 8192 threads
    int k = t >> 5;
    int n4 = (t & 31) * 4;
    float4 v = *(const float4*)(W1 + k * 128 + n4);
    W1t[(n4 + 0) * 256 + k] = f2bf(v.x);
    W1t[(n4 + 1) * 256 + k] = f2bf(v.y);
    W1t[(n4 + 2) * 256 + k] = f2bf(v.z);
    W1t[(n4 + 3) * 256 + k] = f2bf(v.w);
}

// ---------------- pass A: bin edges into 128-node buckets, LDS-staged coalesced flush ----------------

__global__ __launch_bounds__(256) void k_bin(const int* __restrict__ row, const int* __restrict__ col,
                                             const float* __restrict__ ew, int* __restrict__ gcount,
                                             int2* __restrict__ binned, int E, int NB) {
    __shared__ int  cl[MAXNB];      // hist -> local alloc cursor
    __shared__ int  gb2[MAXNB];     // global_base - local_start
    __shared__ int  lpos;
    __shared__ int2 srec[TILE];     // 32 KB bucket-grouped records
    __shared__ u16  sbk[TILE];      // 8 KB bucket id per record
    int t = threadIdx.x;
    int base = blockIdx.x * TILE;
    int M = min(TILE, E - base);
    for (int i = t; i < NB; i += 256) cl[i] = 0;
    if (t == 0) lpos = 0;
    __syncthreads();
    // phase 1: per-tile histogram
#pragma unroll
    for (int i = 0; i < 16; ++i) {
        int e = base + i * 256 + t;
        if (e < E) atomicAdd(&cl[col[e] >> NB_SHIFT], 1);
    }
    __syncthreads();
    // phase 2: reserve global range + local packed region per bucket
    for (int b = t; b < NB; b += 256) {
        int c = cl[b];
        if (c > 0) {
            int ls = atomicAdd(&lpos, c);
            int gb = atomicAdd(gcount + b, c);
            gb2[b] = gb - ls;
            cl[b]  = ls;
        }
    }
    __syncthreads();
    // phase 3: rank into LDS (bucket-grouped)
#pragma unroll
    for (int i = 0; i < 16; ++i) {
        int e = base + i * 256 + t;
        if (e < E) {
            int c = col[e];
            int b = c >> NB_SHIFT;
            int idx = atomicAdd(&cl[b], 1);
            srec[idx] = make_int2(row[e] | ((c & (BNODES - 1)) << 20), __float_as_int(ew[e]));
            sbk[idx]  = (u16)b;
        }
    }
    __syncthreads();
    // phase 4: coalesced flush (consecutive idx in a bucket -> consecutive global addrs)
    for (int idx = t; idx < M; idx += 256) {
        int b = sbk[idx];
        int slot = gb2[b] + idx;
        if (slot < CAPB) binned[(size_t)b * CAPB + slot] = srec[idx];
    }
}

// ---------------- pass B: bucket -> ELL {row, ew} + cnt + dinv ----------------

__global__ __launch_bounds__(256) void k_fill(const int* __restrict__ gcount, const int2* __restrict__ binned,
                                              int* __restrict__ cnt, float* __restrict__ dinv,
                                              int2* __restrict__ ell, int N, int NB) {
    __shared__ int   c128[BNODES];
    __shared__ float d128[BNODES];
    int t = threadIdx.x;
    int b = blockIdx.x;
    if (t < BNODES) { c128[t] = 0; d128[t] = 0.f; }
    __syncthreads();
    int M = min(gcount[b], CAPB);
    int nb0 = b << NB_SHIFT;
    const int2* src = binned + (size_t)b * CAPB;
    for (int j = t; j < M; j += 256) {
        int2 rec = src[j];
        int r  = rec.x & 0xFFFFF;
        int lc = rec.x >> 20;
        int slot = atomicAdd(&c128[lc], 1);
        if (slot < CAP) ell[(size_t)(nb0 + lc) * CAP + slot] = make_int2(r, rec.y);
        atomicAdd(&d128[lc], __int_as_float(rec.y));
    }
    __syncthreads();
    if (t < BNODES) {
        int n = nb0 + t;
        if (n < N) {
            cnt[n]  = c128[t];
            dinv[n] = rsqrtf(1.0f + d128[t]);
        }
    }
}

// ---------------- GEMM1 (MFMA): g0[N,128](fp8) = dinv[n] * (feat[N,256] @ W1) ----------------

__global__ __launch_bounds__(256) void k_gemm1(const float* __restrict__ feat, const u16* __restrict__ W1t,
                                               const float* __restrict__ dinv, u8* __restrict__ h0f, int N) {
    __shared__ u16 As[64 * PK];
    __shared__ u16 Bs[128 * PK];
    int t = threadIdx.x;
    int nb0 = blockIdx.x * 64;
    int wv = t >> 6, lane = t & 63;
    int m16 = lane & 15, quad = lane >> 4;

    f32x4 zero4 = {0.f, 0.f, 0.f, 0.f};
    f32x4 acc[8];
#pragma unroll
    for (int i = 0; i < 8; ++i) acc[i] = zero4;

    for (int half = 0; half < 2; ++half) {
        int k0 = half * 128;
#pragma unroll
        for (int i = 0; i < 8; ++i) {
            int idx = t + 256 * i;
            int r = idx >> 5;
            int c4 = idx & 31;
            int gn = nb0 + r;
            float4 v = (gn < N) ? *(const float4*)(feat + (size_t)gn * 256 + k0 + c4 * 4)
                                : make_float4(0.f, 0.f, 0.f, 0.f);
            ushort4 o;
            o.x = f2bf(v.x); o.y = f2bf(v.y); o.z = f2bf(v.z); o.w = f2bf(v.w);
            *(ushort4*)(As + r * PK + c4 * 4) = o;
        }
#pragma unroll
        for (int i = 0; i < 8; ++i) {
            int idx = t + 256 * i;
            int r = idx >> 4;
            int c = (idx & 15) * 8;
            *(uint4*)(Bs + r * PK + c) = *(const uint4*)(W1t + r * 256 + k0 + c);
        }
        __syncthreads();
        const u16* arow = As + (wv * 16 + m16) * PK + quad * 8;
        const u16* brow = Bs + m16 * PK + quad * 8;
#pragma unroll
        for (int kc = 0; kc < 4; ++kc) {
            bf16x8 a = *(const bf16x8*)(arow + kc * 32);
#pragma unroll
            for (int tn = 0; tn < 8; ++tn) {
                bf16x8 b = *(const bf16x8*)(brow + tn * 16 * PK + kc * 32);
                acc[tn] = __builtin_amdgcn_mfma_f32_16x16x32_bf16(a, b, acc[tn], 0, 0, 0);
            }
        }
        __syncthreads();
    }
    int node0 = nb0 + wv * 16 + quad * 4;
    float dv[4];
#pragma unroll
    for (int r = 0; r < 4; ++r) dv[r] = (node0 + r < N) ? dinv[node0 + r] : 0.f;
#pragma unroll
    for (int tn = 0; tn < 8; ++tn) {
        int hid = tn * 16 + m16;
#pragma unroll
        for (int r = 0; r < 4; ++r) {
            int gn = node0 + r;
            if (gn < N) h0f[(size_t)gn * 128 + hid] = f2fp8(acc[tn][r] * dv[r]);
        }
    }
}

// ---------------- agg1: node-per-16-lane-group fp8 gather + bias + relu + fused GEMM2 ----------------

__global__ __launch_bounds__(256) void k_agg1(const u8* __restrict__ h0f, const float* __restrict__ dinv,
                                              const int* __restrict__ cnt, const int2* __restrict__ ell,
                                              const float* __restrict__ b1, const float* __restrict__ W2,
                                              u16* __restrict__ h2b, int N) {
    __shared__ float s_row[16][132];
    __shared__ float s_w2[2048];
    int t = threadIdx.x;
    int wv = t >> 6, lane = t & 63;
    int g = lane >> 4;        // node sub-group 0..3
    int fl = lane & 15;       // feature lane
    int f = fl * 8;
    int ln = wv * 4 + g;      // local node 0..15
    int n = blockIdx.x * 16 + ln;
    bool active = n < N;

    {
        float4 wa = *(const float4*)(W2 + t * 8);
        float4 wb = *(const float4*)(W2 + t * 8 + 4);
        *(float4*)&s_w2[t * 8]     = wa;
        *(float4*)&s_w2[t * 8 + 4] = wb;
    }

    float acc[8];
#pragma unroll
    for (int j = 0; j < 8; ++j) acc[j] = 0.f;

#define ACC8(V, W)                                                              \
    {                                                                           \
        f32x2 p0 = __builtin_amdgcn_cvt_pk_f32_fp8((V).x, false);               \
        f32x2 p1 = __builtin_amdgcn_cvt_pk_f32_fp8((V).x, true);                \
        f32x2 p2 = __builtin_amdgcn_cvt_pk_f32_fp8((V).y, false);               \
        f32x2 p3 = __builtin_amdgcn_cvt_pk_f32_fp8((V).y, true);                \
        acc[0] += p0[0] * (W); acc[1] += p0[1] * (W);                           \
        acc[2] += p1[0] * (W); acc[3] += p1[1] * (W);                           \
        acc[4] += p2[0] * (W); acc[5] += p2[1] * (W);                           \
        acc[6] += p3[0] * (W); acc[7] += p3[1] * (W);                           \
    }

    if (active) {
        float dn = dinv[n];
        {   // self loop: dn * g0[n]
            uint2 sv = *(const uint2*)(h0f + (size_t)n * 128 + f);
            ACC8(sv, dn);
        }
        int m = min(cnt[n], CAP);
        const int2* ep = ell + (size_t)n * CAP;
        int k = 0;
        for (; k + 3 < m; k += 4) {
            int2 e0 = ep[k], e1 = ep[k + 1], e2 = ep[k + 2], e3 = ep[k + 3];
            uint2 v0 = *(const uint2*)(h0f + (size_t)e0.x * 128 + f);
            uint2 v1 = *(const uint2*)(h0f + (size_t)e1.x * 128 + f);
            uint2 v2 = *(const uint2*)(h0f + (size_t)e2.x * 128 + f);
            uint2 v3 = *(const uint2*)(h0f + (size_t)e3.x * 128 + f);
            float w0 = __int_as_float(e0.y) * dn;
            float w1 = __int_as_float(e1.y) * dn;
            float w2 = __int_as_float(e2.y) * dn;
            float w3 = __int_as_float(e3.y) * dn;
            ACC8(v0, w0);
            ACC8(v1, w1);
            ACC8(v2, w2);
            ACC8(v3, w3);
        }
        for (; k < m; ++k) {
            int2 e = ep[k];
            float w = __int_as_float(e.y) * dn;
            uint2 v = *(const uint2*)(h0f + (size_t)e.x * 128 + f);
            ACC8(v, w);
        }
        float4 bA = *(const float4*)(b1 + f);
        float4 bB = *(const float4*)(b1 + f + 4);
        float4 oA, oB;
        oA.x = fmaxf(acc[0] + bA.x, 0.f); oA.y = fmaxf(acc[1] + bA.y, 0.f);
        oA.z = fmaxf(acc[2] + bA.z, 0.f); oA.w = fmaxf(acc[3] + bA.w, 0.f);
        oB.x = fmaxf(acc[4] + bB.x, 0.f); oB.y = fmaxf(acc[5] + bB.y, 0.f);
        oB.z = fmaxf(acc[6] + bB.z, 0.f); oB.w = fmaxf(acc[7] + bB.w, 0.f);
        *(float4*)&s_row[ln][f]     = oA;
        *(float4*)&s_row[ln][f + 4] = oB;
    }
#undef ACC8
    __syncthreads();

    // fused GEMM2: thread -> (node = t>>4, class = t&15); g2 = dinv * h2
    int nn = t >> 4;
    int c = t & 15;
    int gn = blockIdx.x * 16 + nn;
    float a2 = 0.f;
#pragma unroll
    for (int k = 0; k < 128; ++k) a2 += s_row[nn][k] * s_w2[k * 16 + c];
    if (gn < N) h2b[(size_t)gn * 16 + c] = f2bf(a2 * dinv[gn]);
}

// ---------------- agg2: node-per-8-lane-group bf16 gather + bias2 + log_softmax -> out ----------------

__global__ __launch_bounds__(256) void k_agg2(const u16* __restrict__ g2b, const float* __restrict__ dinv,
                                              const int* __restrict__ cnt, const int2* __restrict__ ell,
                                              const float* __restrict__ b2, float* __restrict__ out, int N) {
    int t = threadIdx.x;
    int wv = t >> 6, lane = t & 63;
    int g = lane >> 3;       // node sub-group 0..7
    int fl = lane & 7;       // feature pair index
    int n = blockIdx.x * 32 + wv * 8 + g;
    if (n >= N) return;
    float dn = dinv[n];
    float2 acc;
    {
        unsigned sv = *(const unsigned*)(g2b + (size_t)n * 16 + fl * 2);
        acc.x = blo(sv) * dn;
        acc.y = bhi(sv) * dn;
    }
    int m = min(cnt[n], CAP);
    const int2* ep = ell + (size_t)n * CAP;
    int k = 0;
    for (; k + 3 < m; k += 4) {
        int2 e0 = ep[k], e1 = ep[k + 1], e2 = ep[k + 2], e3 = ep[k + 3];
        unsigned v0 = *(const unsigned*)(g2b + (size_t)e0.x * 16 + fl * 2);
        unsigned v1 = *(const unsigned*)(g2b + (size_t)e1.x * 16 + fl * 2);
        unsigned v2 = *(const unsigned*)(g2b + (size_t)e2.x * 16 + fl * 2);
        unsigned v3 = *(const unsigned*)(g2b + (size_t)e3.x * 16 + fl * 2);
        float w0 = __int_as_float(e0.y) * dn;
        float w1 = __int_as_float(e1.y) * dn;
        float w2 = __int_as_float(e2.y) * dn;
        float w3 = __int_as_float(e3.y) * dn;
        acc.x += blo(v0) * w0 + blo(v1) * w1 + blo(v2) * w2 + blo(v3) * w3;
        acc.y += bhi(v0) * w0 + bhi(v1) * w1 + bhi(v2) * w2 + bhi(v3) * w3;
    }
    for (; k < m; ++k) {
        int2 e = ep[k];
        float w = __int_as_float(e.y) * dn;
        unsigned v = *(const unsigned*)(g2b + (size_t)e.x * 16 + fl * 2);
        acc.x += blo(v) * w;
        acc.y += bhi(v) * w;
    }
    float v0 = acc.x + b2[fl * 2];
    float v1 = acc.y + b2[fl * 2 + 1];
    float mx = fmaxf(v0, v1);
    mx = fmaxf(mx, __shfl_xor(mx, 1));
    mx = fmaxf(mx, __shfl_xor(mx, 2));
    mx = fmaxf(mx, __shfl_xor(mx, 4));
    float ex = __expf(v0 - mx) + __expf(v1 - mx);
    ex += __shfl_xor(ex, 1);
    ex += __shfl_xor(ex, 2);
    ex += __shfl_xor(ex, 4);
    float lse = mx + __logf(ex);
    *(float2*)(out + (size_t)n * 16 + fl * 2) = make_float2(v0 - lse, v1 - lse);
}

// ---------------- launch ----------------

extern "C" void kernel_launch(void* const* d_in, const int* in_sizes, int n_in,
                              void* d_out, int out_size, void* d_ws, size_t ws_size,
                              hipStream_t stream) {
    const float* feat = (const float*)d_in[0];
    const int*   eidx = (const int*)d_in[1];
    const float* ew   = (const float*)d_in[2];
    const float* W1   = (const float*)d_in[3];
    const float* b1   = (const float*)d_in[4];
    const float* W2   = (const float*)d_in[5];
    const float* b2   = (const float*)d_in[6];
    float* out = (float*)d_out;

    int N = in_sizes[0] / 256;
    int E = in_sizes[2];
    const int* row = eidx;
    const int* col = eidx + E;
    int NB = (N + BNODES - 1) >> NB_SHIFT;

    char* ws = (char*)d_ws;
    size_t off = 0;
    auto take = [&](size_t bytes) { void* p = ws + off; off += (bytes + 255) & ~(size_t)255; return p; };
    int*   cnt    = (int*)take((size_t)N * 4);
    float* dinv   = (float*)take((size_t)N * 4);
    int*   gcount = (int*)take((size_t)NB * 4);
    u16*   W1t    = (u16*)take((size_t)128 * 256 * 2);
    int2*  ell    = (int2*)take((size_t)N * CAP * 8);
    size_t ubytes = (size_t)NB * CAPB * 8;                    // binned
    size_t h0fb   = (size_t)N * 128;                          // h0 fp8
    void*  uni    = take(ubytes > h0fb ? ubytes : h0fb);      // aliased: binned dead before gemm1
    u16*   h2b    = (u16*)take((size_t)N * 16 * 2);
    int2*  binned = (int2*)uni;
    u8*    h0f    = (u8*)uni;

    auto cdiv = [](long long a, long long b) { return (int)((a + b - 1) / b); };

    k_zero  <<<cdiv(NB, 256), 256, 0, stream>>>(gcount, NB);
    k_bin   <<<cdiv(E, TILE), 256, 0, stream>>>(row, col, ew, gcount, binned, E, NB);
    k_fill  <<<NB, 256, 0, stream>>>(gcount, binned, cnt, dinv, ell, N, NB);
    k_prepw <<<32, 256, 0, stream>>>(W1, W1t);

    k_gemm1 <<<cdiv(N, 64), 256, 0, stream>>>(feat, W1t, dinv, h0f, N);
    k_agg1  <<<cdiv(N, 16), 256, 0, stream>>>(h0f, dinv, cnt, ell, b1, W2, h2b, N);
    k_agg2  <<<cdiv(N, 32), 256, 0, stream>>>(h2b, dinv, cnt, ell, b2, out, N);
}